// Round 3
// baseline (372.718 us; speedup 1.0000x reference)
//
#include <hip/hip_runtime.h>
#include <hip/hip_bf16.h>

// ZorroPP: the [C,M] sketch never needs materializing.
// acc[c]  = exp(-t/64)*rowsum_sketch[c] + 0.01*rowsum_noise[c]
// mu[c]   = g[c]/M * ( acc[c] + (1/t)*g[c]*colsum_x[c]*len(h) )
// out = s*(x - mu) @ W + b,  s = 1/((1+1e-6)*sqrt(0.375+1e-6))
//
// R3: muhat was latency-bound (VGPR=28 -> ~2 loads in flight). Now one block
// per (row, stream): 8192 blocks, each reads one contiguous 32KB row with 8
// explicitly-batched float4 loads/thread, weighted atomicAdd into acc[c].

#define SPLITK 8

// colsum[c] = sum_b x[b,c]; grid (C/256, B/32)
__global__ __launch_bounds__(256) void colsum_kernel(const float* __restrict__ x,
                                                     float* __restrict__ colsum,
                                                     int Cdim) {
    int c = blockIdx.x * 256 + threadIdx.x;
    int b0 = blockIdx.y * 32;
    float acc = 0.0f;
#pragma unroll 8
    for (int b = b0; b < b0 + 32; ++b)
        acc += x[(size_t)b * Cdim + c];
    atomicAdd(&colsum[c], acc);
}

// grid (C, 2): blockIdx.y==0 -> sketch (weight=exp(-t/64)), ==1 -> noise (0.01)
__global__ __launch_bounds__(256) void rowsum_kernel(const float* __restrict__ sk,
                                                     const float* __restrict__ noise,
                                                     const int* __restrict__ t_ptr,
                                                     float* __restrict__ acc,
                                                     int Msk) {
    int row = blockIdx.x;
    const float* src = (blockIdx.y == 0) ? sk : noise;
    const float4* p = reinterpret_cast<const float4*>(src + (size_t)row * Msk);
    int n4 = Msk >> 2;
    int tid = threadIdx.x;

    float sum = 0.0f;
    int base = 0;
    // main: chunks of 2048 float4 (256 threads x 8), fully batched loads
    for (; base + 2048 <= n4; base += 2048) {
        const float4* q = p + base + tid;
        float4 v0 = q[0 * 256];
        float4 v1 = q[1 * 256];
        float4 v2 = q[2 * 256];
        float4 v3 = q[3 * 256];
        float4 v4 = q[4 * 256];
        float4 v5 = q[5 * 256];
        float4 v6 = q[6 * 256];
        float4 v7 = q[7 * 256];
        float s0 = (v0.x + v0.y) + (v0.z + v0.w);
        float s1 = (v1.x + v1.y) + (v1.z + v1.w);
        float s2 = (v2.x + v2.y) + (v2.z + v2.w);
        float s3 = (v3.x + v3.y) + (v3.z + v3.w);
        float s4 = (v4.x + v4.y) + (v4.z + v4.w);
        float s5 = (v5.x + v5.y) + (v5.z + v5.w);
        float s6 = (v6.x + v6.y) + (v6.z + v6.w);
        float s7 = (v7.x + v7.y) + (v7.z + v7.w);
        sum += ((s0 + s1) + (s2 + s3)) + ((s4 + s5) + (s6 + s7));
    }
    for (int i = base + tid; i < n4; i += 256) {
        float4 v = p[i];
        sum += (v.x + v.y) + (v.z + v.w);
    }

#pragma unroll
    for (int off = 32; off > 0; off >>= 1)
        sum += __shfl_down(sum, off);

    __shared__ float red[4];
    int wid = tid >> 6;
    if ((tid & 63) == 0) red[wid] = sum;
    __syncthreads();
    if (tid == 0) {
        float total = (red[0] + red[1]) + (red[2] + red[3]);
        float w;
        if (blockIdx.y == 0) {
            float t = (float)(*t_ptr);
            w = __expf(-t / 64.0f);
        } else {
            w = 0.01f;
        }
        atomicAdd(&acc[row], w * total);
    }
}

// mu[c] = g[c]/M * (acc[c] + (1/t)*g[c]*colsum[c]*hcount)
__global__ __launch_bounds__(256) void finalize_kernel(const float* __restrict__ accp,
                                                       const float* __restrict__ g,
                                                       const float* __restrict__ colsum,
                                                       const int* __restrict__ t_ptr,
                                                       float* __restrict__ mu,
                                                       int Cdim, int Msk, float hcount) {
    int c = blockIdx.x * 256 + threadIdx.x;
    if (c >= Cdim) return;
    float t = (float)(*t_ptr);
    float kappa = 1.0f / t;
    float gc = g[c];
    mu[c] = gc / (float)Msk * (accp[c] + kappa * gc * colsum[c] * hcount);
}

// out[i,k] = b[k] (atomic-fallback path only)
__global__ __launch_bounds__(256) void init_out_kernel(const float* __restrict__ bias,
                                                       float* __restrict__ out,
                                                       int Kdim, int total) {
    int i = blockIdx.x * 256 + threadIdx.x;
    if (i < total) out[i] = bias[i % Kdim];
}

// s*(x - mu) @ W over the z-th C-chunk. grid (B/64, ceil(K/64), SPLITK).
template <bool ATOMIC>
__global__ __launch_bounds__(256, 4) void gemm_kernel(const float* __restrict__ x,
                                                      const float* __restrict__ W,
                                                      const float* __restrict__ mu,
                                                      float* __restrict__ outp,
                                                      int Bdim, int Cdim, int Kdim,
                                                      int cchunk, float s) {
    __shared__ float As[32][68];   // [k][m]
    __shared__ float Bs[32][72];   // [k][n]

    int row0 = blockIdx.x * 64;
    int col0 = blockIdx.y * 64;
    int cbeg = blockIdx.z * cchunk;

    int tid = threadIdx.x;
    int tx = tid & 15;
    int ty = tid >> 4;
    int a_r = tid >> 2;            // 0..63
    int a_k = (tid & 3) * 4;       // 0,4,8,12  (+16 for second float4)
    int b_k = tid >> 3;            // 0..31
    int b_c = (tid & 7) * 8;       // 0,8,..,56 (+4 for second float4)

    float acc[4][4] = {};

    for (int c0 = cbeg; c0 < cbeg + cchunk; c0 += 32) {
        const float* xr = &x[(size_t)(row0 + a_r) * Cdim + c0 + a_k];
        float4 a0 = *reinterpret_cast<const float4*>(xr);
        float4 a1 = *reinterpret_cast<const float4*>(xr + 16);
        float4 m0 = *reinterpret_cast<const float4*>(&mu[c0 + a_k]);
        float4 m1 = *reinterpret_cast<const float4*>(&mu[c0 + a_k + 16]);

        const float* wr = &W[(size_t)(c0 + b_k) * Kdim + col0 + b_c];
        int cb = col0 + b_c;
        float4 b0, b1;
        if (cb + 7 < Kdim) {
            b0 = *reinterpret_cast<const float4*>(wr);
            b1 = *reinterpret_cast<const float4*>(wr + 4);
        } else {
            b0.x = (cb + 0 < Kdim) ? wr[0] : 0.0f;
            b0.y = (cb + 1 < Kdim) ? wr[1] : 0.0f;
            b0.z = (cb + 2 < Kdim) ? wr[2] : 0.0f;
            b0.w = (cb + 3 < Kdim) ? wr[3] : 0.0f;
            b1.x = (cb + 4 < Kdim) ? wr[4] : 0.0f;
            b1.y = (cb + 5 < Kdim) ? wr[5] : 0.0f;
            b1.z = (cb + 6 < Kdim) ? wr[6] : 0.0f;
            b1.w = (cb + 7 < Kdim) ? wr[7] : 0.0f;
        }

        As[a_k + 0][a_r] = s * (a0.x - m0.x);
        As[a_k + 1][a_r] = s * (a0.y - m0.y);
        As[a_k + 2][a_r] = s * (a0.z - m0.z);
        As[a_k + 3][a_r] = s * (a0.w - m0.w);
        As[a_k + 16][a_r] = s * (a1.x - m1.x);
        As[a_k + 17][a_r] = s * (a1.y - m1.y);
        As[a_k + 18][a_r] = s * (a1.z - m1.z);
        As[a_k + 19][a_r] = s * (a1.w - m1.w);
        *reinterpret_cast<float4*>(&Bs[b_k][b_c]) = b0;
        *reinterpret_cast<float4*>(&Bs[b_k][b_c + 4]) = b1;

        __syncthreads();
#pragma unroll
        for (int kk = 0; kk < 32; ++kk) {
            float4 a = *reinterpret_cast<const float4*>(&As[kk][ty * 4]);
            float4 b = *reinterpret_cast<const float4*>(&Bs[kk][tx * 4]);
            acc[0][0] += a.x * b.x; acc[0][1] += a.x * b.y;
            acc[0][2] += a.x * b.z; acc[0][3] += a.x * b.w;
            acc[1][0] += a.y * b.x; acc[1][1] += a.y * b.y;
            acc[1][2] += a.y * b.z; acc[1][3] += a.y * b.w;
            acc[2][0] += a.z * b.x; acc[2][1] += a.z * b.y;
            acc[2][2] += a.z * b.z; acc[2][3] += a.z * b.w;
            acc[3][0] += a.w * b.x; acc[3][1] += a.w * b.y;
            acc[3][2] += a.w * b.z; acc[3][3] += a.w * b.w;
        }
        __syncthreads();
    }

#pragma unroll
    for (int j = 0; j < 4; ++j) {
        int row = row0 + ty * 4 + j;
        int col = col0 + tx * 4;
        if (ATOMIC) {
#pragma unroll
            for (int l = 0; l < 4; ++l)
                if (col + l < Kdim)
                    atomicAdd(&outp[(size_t)row * Kdim + col + l], acc[j][l]);
        } else {
            float* pp = &outp[((size_t)blockIdx.z * Bdim + row) * Kdim + col];
            if (col + 3 < Kdim) {
                float4 v;
                v.x = acc[j][0]; v.y = acc[j][1]; v.z = acc[j][2]; v.w = acc[j][3];
                *reinterpret_cast<float4*>(pp) = v;
            } else {
#pragma unroll
                for (int l = 0; l < 4; ++l)
                    if (col + l < Kdim) pp[l] = acc[j][l];
            }
        }
    }
}

// out = bias + sum_z partial[z]; flat float4 over B*K
__global__ __launch_bounds__(256) void reduce_kernel(const float* __restrict__ part,
                                                     const float* __restrict__ bias,
                                                     float* __restrict__ out,
                                                     int total4, int Kdim, int perz) {
    int i = blockIdx.x * 256 + threadIdx.x;
    if (i >= total4) return;
    const float4* p4 = reinterpret_cast<const float4*>(part);
    float4 sum = p4[i];
#pragma unroll
    for (int z = 1; z < SPLITK; ++z) {
        float4 v = p4[(size_t)z * (perz >> 2) + i];
        sum.x += v.x; sum.y += v.y; sum.z += v.z; sum.w += v.w;
    }
    int e = i * 4;
    sum.x += bias[(e + 0) % Kdim];
    sum.y += bias[(e + 1) % Kdim];
    sum.z += bias[(e + 2) % Kdim];
    sum.w += bias[(e + 3) % Kdim];
    reinterpret_cast<float4*>(out)[i] = sum;
}

extern "C" void kernel_launch(void* const* d_in, const int* in_sizes, int n_in,
                              void* d_out, int out_size, void* d_ws, size_t ws_size,
                              hipStream_t stream) {
    const float* x      = (const float*)d_in[0];   // [B, C]
    const float* sk     = (const float*)d_in[1];   // [C, M]
    const float* g      = (const float*)d_in[2];   // [C]
    const float* noise  = (const float*)d_in[3];   // [C, M]
    const float* W      = (const float*)d_in[4];   // [C, K]
    const float* bias   = (const float*)d_in[5];   // [K]
    // d_in[6] = h: only its LENGTH matters (sum of bincount == len(h))
    const int* t_ptr    = (const int*)d_in[7];

    int C    = in_sizes[2];
    int Bdim = in_sizes[0] / C;
    int Msk  = in_sizes[1] / C;
    int Kdim = in_sizes[5];
    float hcount = (float)in_sizes[6];

    float* colsum = (float*)d_ws;            // C floats
    float* accp   = colsum + C;              // C floats
    float* mu     = accp + C;                // C floats
    float* part   = mu + C;                  // SPLITK*B*K floats (if it fits)

    size_t need = (size_t)(3 * C + SPLITK * Bdim * Kdim) * sizeof(float);
    bool use_partial = ws_size >= need;

    float s = (float)(1.0 / ((1.0 + 1e-6) * sqrt(0.375 + 1e-6)));
    int cchunk = C / SPLITK;

    // 1) colsum = acc = 0
    hipMemsetAsync(colsum, 0, 2 * C * sizeof(float), stream);
    // 2) colsum of x
    {
        dim3 grid(C / 256, Bdim / 32);
        colsum_kernel<<<grid, 256, 0, stream>>>(x, colsum, C);
    }
    // 3) weighted rowsums of sketch_mu and noise -> acc
    {
        dim3 grid(C, 2);
        rowsum_kernel<<<grid, 256, 0, stream>>>(sk, noise, t_ptr, accp, Msk);
    }
    // 4) finalize mu
    finalize_kernel<<<(C + 255) / 256, 256, 0, stream>>>(accp, g, colsum, t_ptr, mu,
                                                         C, Msk, hcount);
    // 5+6) GEMM (split-K) and combine
    dim3 ggrid(Bdim / 64, (Kdim + 63) / 64, SPLITK);
    if (use_partial) {
        gemm_kernel<false><<<ggrid, 256, 0, stream>>>(x, W, mu, part, Bdim, C, Kdim,
                                                      cchunk, s);
        int perz = Bdim * Kdim;
        int total4 = perz / 4;
        reduce_kernel<<<(total4 + 255) / 256, 256, 0, stream>>>(part, bias,
                                                                (float*)d_out,
                                                                total4, Kdim, perz);
    } else {
        int total = Bdim * Kdim;
        init_out_kernel<<<(total + 255) / 256, 256, 0, stream>>>(bias, (float*)d_out,
                                                                 Kdim, total);
        gemm_kernel<true><<<ggrid, 256, 0, stream>>>(x, W, mu, (float*)d_out, Bdim, C,
                                                     Kdim, cchunk, s);
    }
}

// Round 5
// 341.866 us; speedup vs baseline: 1.0902x; 1.0902x over previous
//
#include <hip/hip_runtime.h>
#include <hip/hip_bf16.h>

// ZorroPP: the [C,M] sketch never needs materializing.
// mu[c] = g[c]/M * ( exp(-t/64)*rowsum_sketch[c] + 0.01*rowsum_noise[c]
//                    + (1/t)*g[c]*colsum_x[c]*len(h) )
// out = s*(x - mu) @ W + b,  s = 1/((1+1e-6)*sqrt(0.375+1e-6))
//
// R4 (resubmit — R4 bench never ran: GPU acquisition timeout):
// rowsum had VGPR=20 -> compiler serialized the loads (latency-bound,
// 2.7 TB/s eff). Fix: explicit 16-float4 load phase + sched_barrier(0) to
// pin loads before adds; nontemporal loads to keep x/W L3-resident for the
// GEMM; colsum gets 1024 blocks + 8 batched loads; finalize fused in.

#define SPLITK 8

typedef float f32x4 __attribute__((ext_vector_type(4)));

// colsum[c] = sum_b x[b,c]; grid (C/256, B/8), 8 batched loads per thread
__global__ __launch_bounds__(256) void colsum_kernel(const float* __restrict__ x,
                                                     float* __restrict__ colsum,
                                                     int Cdim) {
    int c = blockIdx.x * 256 + threadIdx.x;
    const float* p = x + (size_t)(blockIdx.y * 8) * Cdim + c;
    float r0 = p[0 * (size_t)Cdim];
    float r1 = p[1 * (size_t)Cdim];
    float r2 = p[2 * (size_t)Cdim];
    float r3 = p[3 * (size_t)Cdim];
    float r4 = p[4 * (size_t)Cdim];
    float r5 = p[5 * (size_t)Cdim];
    float r6 = p[6 * (size_t)Cdim];
    float r7 = p[7 * (size_t)Cdim];
    __builtin_amdgcn_sched_barrier(0);
    float acc = ((r0 + r1) + (r2 + r3)) + ((r4 + r5) + (r6 + r7));
    atomicAdd(&colsum[c], acc);
}

// One block per channel: weighted rowsums of sketch+noise, fused finalize.
// Requires colsum already computed (stream-ordered).
__global__ __launch_bounds__(256, 4) void rowsum_kernel(const float* __restrict__ sk,
                                                        const float* __restrict__ noise,
                                                        const float* __restrict__ g,
                                                        const float* __restrict__ colsum,
                                                        const int* __restrict__ t_ptr,
                                                        float* __restrict__ mu,
                                                        int Msk, float hcount) {
    int row = blockIdx.x;
    int tid = threadIdx.x;
    const f32x4* ps = reinterpret_cast<const f32x4*>(sk + (size_t)row * Msk);
    const f32x4* pn = reinterpret_cast<const f32x4*>(noise + (size_t)row * Msk);
    int n4 = Msk >> 2;

    float ss = 0.0f, sn = 0.0f;
    int base = 0;
    for (; base + 2048 <= n4; base += 2048) {
        const f32x4* qs = ps + base + tid;
        const f32x4* qn = pn + base + tid;
        f32x4 a0 = __builtin_nontemporal_load(qs + 0 * 256);
        f32x4 a1 = __builtin_nontemporal_load(qs + 1 * 256);
        f32x4 a2 = __builtin_nontemporal_load(qs + 2 * 256);
        f32x4 a3 = __builtin_nontemporal_load(qs + 3 * 256);
        f32x4 a4 = __builtin_nontemporal_load(qs + 4 * 256);
        f32x4 a5 = __builtin_nontemporal_load(qs + 5 * 256);
        f32x4 a6 = __builtin_nontemporal_load(qs + 6 * 256);
        f32x4 a7 = __builtin_nontemporal_load(qs + 7 * 256);
        f32x4 b0 = __builtin_nontemporal_load(qn + 0 * 256);
        f32x4 b1 = __builtin_nontemporal_load(qn + 1 * 256);
        f32x4 b2 = __builtin_nontemporal_load(qn + 2 * 256);
        f32x4 b3 = __builtin_nontemporal_load(qn + 3 * 256);
        f32x4 b4 = __builtin_nontemporal_load(qn + 4 * 256);
        f32x4 b5 = __builtin_nontemporal_load(qn + 5 * 256);
        f32x4 b6 = __builtin_nontemporal_load(qn + 6 * 256);
        f32x4 b7 = __builtin_nontemporal_load(qn + 7 * 256);
        __builtin_amdgcn_sched_barrier(0);
        float s0 = (a0.x + a0.y) + (a0.z + a0.w);
        float s1 = (a1.x + a1.y) + (a1.z + a1.w);
        float s2 = (a2.x + a2.y) + (a2.z + a2.w);
        float s3 = (a3.x + a3.y) + (a3.z + a3.w);
        float s4 = (a4.x + a4.y) + (a4.z + a4.w);
        float s5 = (a5.x + a5.y) + (a5.z + a5.w);
        float s6 = (a6.x + a6.y) + (a6.z + a6.w);
        float s7 = (a7.x + a7.y) + (a7.z + a7.w);
        float t0 = (b0.x + b0.y) + (b0.z + b0.w);
        float t1 = (b1.x + b1.y) + (b1.z + b1.w);
        float t2 = (b2.x + b2.y) + (b2.z + b2.w);
        float t3 = (b3.x + b3.y) + (b3.z + b3.w);
        float t4 = (b4.x + b4.y) + (b4.z + b4.w);
        float t5 = (b5.x + b5.y) + (b5.z + b5.w);
        float t6 = (b6.x + b6.y) + (b6.z + b6.w);
        float t7 = (b7.x + b7.y) + (b7.z + b7.w);
        ss += ((s0 + s1) + (s2 + s3)) + ((s4 + s5) + (s6 + s7));
        sn += ((t0 + t1) + (t2 + t3)) + ((t4 + t5) + (t6 + t7));
    }
    for (int i = base + tid; i < n4; i += 256) {
        f32x4 v = ps[i];
        f32x4 w = pn[i];
        ss += (v.x + v.y) + (v.z + v.w);
        sn += (w.x + w.y) + (w.z + w.w);
    }

#pragma unroll
    for (int off = 32; off > 0; off >>= 1) {
        ss += __shfl_down(ss, off);
        sn += __shfl_down(sn, off);
    }
    __shared__ float red[2][4];
    int wid = tid >> 6;
    if ((tid & 63) == 0) { red[0][wid] = ss; red[1][wid] = sn; }
    __syncthreads();
    if (tid == 0) {
        float sst = (red[0][0] + red[0][1]) + (red[0][2] + red[0][3]);
        float snt = (red[1][0] + red[1][1]) + (red[1][2] + red[1][3]);
        float t = (float)(*t_ptr);
        float decay = __expf(-t / 64.0f);
        float kappa = 1.0f / t;
        float gc = g[row];
        float acc = decay * sst + 0.01f * snt;
        mu[row] = gc / (float)Msk * (acc + kappa * gc * colsum[row] * hcount);
    }
}

// out[i,k] = b[k] (atomic-fallback path only)
__global__ __launch_bounds__(256) void init_out_kernel(const float* __restrict__ bias,
                                                       float* __restrict__ out,
                                                       int Kdim, int total) {
    int i = blockIdx.x * 256 + threadIdx.x;
    if (i < total) out[i] = bias[i % Kdim];
}

// s*(x - mu) @ W over the z-th C-chunk. grid (B/64, ceil(K/64), SPLITK).
template <bool ATOMIC>
__global__ __launch_bounds__(256, 4) void gemm_kernel(const float* __restrict__ x,
                                                      const float* __restrict__ W,
                                                      const float* __restrict__ mu,
                                                      float* __restrict__ outp,
                                                      int Bdim, int Cdim, int Kdim,
                                                      int cchunk, float s) {
    __shared__ float As[32][68];   // [k][m]
    __shared__ float Bs[32][72];   // [k][n]

    int row0 = blockIdx.x * 64;
    int col0 = blockIdx.y * 64;
    int cbeg = blockIdx.z * cchunk;

    int tid = threadIdx.x;
    int tx = tid & 15;
    int ty = tid >> 4;
    int a_r = tid >> 2;            // 0..63
    int a_k = (tid & 3) * 4;       // 0,4,8,12  (+16 for second float4)
    int b_k = tid >> 3;            // 0..31
    int b_c = (tid & 7) * 8;       // 0,8,..,56 (+4 for second float4)

    float acc[4][4] = {};

    for (int c0 = cbeg; c0 < cbeg + cchunk; c0 += 32) {
        const float* xr = &x[(size_t)(row0 + a_r) * Cdim + c0 + a_k];
        float4 a0 = *reinterpret_cast<const float4*>(xr);
        float4 a1 = *reinterpret_cast<const float4*>(xr + 16);
        float4 m0 = *reinterpret_cast<const float4*>(&mu[c0 + a_k]);
        float4 m1 = *reinterpret_cast<const float4*>(&mu[c0 + a_k + 16]);

        const float* wr = &W[(size_t)(c0 + b_k) * Kdim + col0 + b_c];
        int cb = col0 + b_c;
        float4 b0, b1;
        if (cb + 7 < Kdim) {
            b0 = *reinterpret_cast<const float4*>(wr);
            b1 = *reinterpret_cast<const float4*>(wr + 4);
        } else {
            b0.x = (cb + 0 < Kdim) ? wr[0] : 0.0f;
            b0.y = (cb + 1 < Kdim) ? wr[1] : 0.0f;
            b0.z = (cb + 2 < Kdim) ? wr[2] : 0.0f;
            b0.w = (cb + 3 < Kdim) ? wr[3] : 0.0f;
            b1.x = (cb + 4 < Kdim) ? wr[4] : 0.0f;
            b1.y = (cb + 5 < Kdim) ? wr[5] : 0.0f;
            b1.z = (cb + 6 < Kdim) ? wr[6] : 0.0f;
            b1.w = (cb + 7 < Kdim) ? wr[7] : 0.0f;
        }

        As[a_k + 0][a_r] = s * (a0.x - m0.x);
        As[a_k + 1][a_r] = s * (a0.y - m0.y);
        As[a_k + 2][a_r] = s * (a0.z - m0.z);
        As[a_k + 3][a_r] = s * (a0.w - m0.w);
        As[a_k + 16][a_r] = s * (a1.x - m1.x);
        As[a_k + 17][a_r] = s * (a1.y - m1.y);
        As[a_k + 18][a_r] = s * (a1.z - m1.z);
        As[a_k + 19][a_r] = s * (a1.w - m1.w);
        *reinterpret_cast<float4*>(&Bs[b_k][b_c]) = b0;
        *reinterpret_cast<float4*>(&Bs[b_k][b_c + 4]) = b1;

        __syncthreads();
#pragma unroll
        for (int kk = 0; kk < 32; ++kk) {
            float4 a = *reinterpret_cast<const float4*>(&As[kk][ty * 4]);
            float4 b = *reinterpret_cast<const float4*>(&Bs[kk][tx * 4]);
            acc[0][0] += a.x * b.x; acc[0][1] += a.x * b.y;
            acc[0][2] += a.x * b.z; acc[0][3] += a.x * b.w;
            acc[1][0] += a.y * b.x; acc[1][1] += a.y * b.y;
            acc[1][2] += a.y * b.z; acc[1][3] += a.y * b.w;
            acc[2][0] += a.z * b.x; acc[2][1] += a.z * b.y;
            acc[2][2] += a.z * b.z; acc[2][3] += a.z * b.w;
            acc[3][0] += a.w * b.x; acc[3][1] += a.w * b.y;
            acc[3][2] += a.w * b.z; acc[3][3] += a.w * b.w;
        }
        __syncthreads();
    }

#pragma unroll
    for (int j = 0; j < 4; ++j) {
        int row = row0 + ty * 4 + j;
        int col = col0 + tx * 4;
        if (ATOMIC) {
#pragma unroll
            for (int l = 0; l < 4; ++l)
                if (col + l < Kdim)
                    atomicAdd(&outp[(size_t)row * Kdim + col + l], acc[j][l]);
        } else {
            float* pp = &outp[((size_t)blockIdx.z * Bdim + row) * Kdim + col];
            if (col + 3 < Kdim) {
                float4 v;
                v.x = acc[j][0]; v.y = acc[j][1]; v.z = acc[j][2]; v.w = acc[j][3];
                *reinterpret_cast<float4*>(pp) = v;
            } else {
#pragma unroll
                for (int l = 0; l < 4; ++l)
                    if (col + l < Kdim) pp[l] = acc[j][l];
            }
        }
    }
}

// out = bias + sum_z partial[z]; flat float4 over B*K
__global__ __launch_bounds__(256) void reduce_kernel(const float* __restrict__ part,
                                                     const float* __restrict__ bias,
                                                     float* __restrict__ out,
                                                     int total4, int Kdim, int perz) {
    int i = blockIdx.x * 256 + threadIdx.x;
    if (i >= total4) return;
    const float4* p4 = reinterpret_cast<const float4*>(part);
    float4 sum = p4[i];
#pragma unroll
    for (int z = 1; z < SPLITK; ++z) {
        float4 v = p4[(size_t)z * (perz >> 2) + i];
        sum.x += v.x; sum.y += v.y; sum.z += v.z; sum.w += v.w;
    }
    int e = i * 4;
    sum.x += bias[(e + 0) % Kdim];
    sum.y += bias[(e + 1) % Kdim];
    sum.z += bias[(e + 2) % Kdim];
    sum.w += bias[(e + 3) % Kdim];
    reinterpret_cast<float4*>(out)[i] = sum;
}

extern "C" void kernel_launch(void* const* d_in, const int* in_sizes, int n_in,
                              void* d_out, int out_size, void* d_ws, size_t ws_size,
                              hipStream_t stream) {
    const float* x      = (const float*)d_in[0];   // [B, C]
    const float* sk     = (const float*)d_in[1];   // [C, M]
    const float* g      = (const float*)d_in[2];   // [C]
    const float* noise  = (const float*)d_in[3];   // [C, M]
    const float* W      = (const float*)d_in[4];   // [C, K]
    const float* bias   = (const float*)d_in[5];   // [K]
    // d_in[6] = h: only its LENGTH matters (sum of bincount == len(h))
    const int* t_ptr    = (const int*)d_in[7];

    int C    = in_sizes[2];
    int Bdim = in_sizes[0] / C;
    int Msk  = in_sizes[1] / C;
    int Kdim = in_sizes[5];
    float hcount = (float)in_sizes[6];

    float* colsum = (float*)d_ws;            // C floats
    float* mu     = colsum + C;              // C floats
    float* part   = mu + C;                  // SPLITK*B*K floats (if it fits)

    size_t need = (size_t)(2 * C + SPLITK * Bdim * Kdim) * sizeof(float);
    bool use_partial = ws_size >= need;

    float s = (float)(1.0 / ((1.0 + 1e-6) * sqrt(0.375 + 1e-6)));
    int cchunk = C / SPLITK;

    // 1) colsum = 0
    hipMemsetAsync(colsum, 0, C * sizeof(float), stream);
    // 2) colsum of x (1024 blocks, 8 batched loads/thread)
    {
        dim3 grid(C / 256, Bdim / 8);
        colsum_kernel<<<grid, 256, 0, stream>>>(x, colsum, C);
    }
    // 3) weighted rowsums + fused mu finalize (16 loads in flight/thread)
    rowsum_kernel<<<C, 256, 0, stream>>>(sk, noise, g, colsum, t_ptr, mu, Msk, hcount);
    // 4+5) GEMM (split-K) and combine
    dim3 ggrid(Bdim / 64, (Kdim + 63) / 64, SPLITK);
    if (use_partial) {
        gemm_kernel<false><<<ggrid, 256, 0, stream>>>(x, W, mu, part, Bdim, C, Kdim,
                                                      cchunk, s);
        int perz = Bdim * Kdim;
        int total4 = perz / 4;
        reduce_kernel<<<(total4 + 255) / 256, 256, 0, stream>>>(part, bias,
                                                                (float*)d_out,
                                                                total4, Kdim, perz);
    } else {
        int total = Bdim * Kdim;
        init_out_kernel<<<(total + 255) / 256, 256, 0, stream>>>(bias, (float*)d_out,
                                                                 Kdim, total);
        gemm_kernel<true><<<ggrid, 256, 0, stream>>>(x, W, mu, (float*)d_out, Bdim, C,
                                                     Kdim, cchunk, s);
    }
}

// Round 7
// 313.336 us; speedup vs baseline: 1.1895x; 1.0911x over previous
//
#include <hip/hip_runtime.h>
#include <hip/hip_bf16.h>

// ZorroPP: the [C,M] sketch never needs materializing.
// mu[c] = g[c]/M * ( exp(-t/64)*rowsum_sketch[c] + 0.01*rowsum_noise[c]
//                    + (1/t)*g[c]*colsum_x[c]*len(h) )
// out = s*(x - mu) @ W + b,  s = 1/((1+1e-6)*sqrt(0.375+1e-6))
//
// R6 resubmit (R6 bench never ran: GPU acquisition timeout):
// GEMM moved from fp32 VALU (157 TF pipe) to split-bf16 MFMA (2.5 PF
// pipe): A,W each split hi+lo bf16; acc += hh + hl + lh (lo*lo dropped,
// ~2^-16 rel). 64x64x32 tile, both operands K-contiguous in LDS [64][40]
// shorts (20-bank row stride -> 2-way conflicts = free; rows 80 B keep
// ds_read_b128 aligned). Split-K=8 partials + reduce, as before.

#define SPLITK 8

typedef float f32x4 __attribute__((ext_vector_type(4)));
typedef short bf16x8 __attribute__((ext_vector_type(8)));

__device__ __forceinline__ short f2bf(float f) {
    unsigned u = __float_as_uint(f);
    unsigned r = (u + 0x7FFFu + ((u >> 16) & 1u)) >> 16;   // RNE
    return (short)r;
}
__device__ __forceinline__ float bf2f(short b) {
    return __uint_as_float(((unsigned)(unsigned short)b) << 16);
}

// colsum[c] = sum_b x[b,c]; grid (C/256, B/8), 8 batched loads per thread
__global__ __launch_bounds__(256) void colsum_kernel(const float* __restrict__ x,
                                                     float* __restrict__ colsum,
                                                     int Cdim) {
    int c = blockIdx.x * 256 + threadIdx.x;
    const float* p = x + (size_t)(blockIdx.y * 8) * Cdim + c;
    float r0 = p[0 * (size_t)Cdim];
    float r1 = p[1 * (size_t)Cdim];
    float r2 = p[2 * (size_t)Cdim];
    float r3 = p[3 * (size_t)Cdim];
    float r4 = p[4 * (size_t)Cdim];
    float r5 = p[5 * (size_t)Cdim];
    float r6 = p[6 * (size_t)Cdim];
    float r7 = p[7 * (size_t)Cdim];
    __builtin_amdgcn_sched_barrier(0);
    float acc = ((r0 + r1) + (r2 + r3)) + ((r4 + r5) + (r6 + r7));
    atomicAdd(&colsum[c], acc);
}

// One block per channel: weighted rowsums of sketch+noise, fused finalize.
__global__ __launch_bounds__(256, 4) void rowsum_kernel(const float* __restrict__ sk,
                                                        const float* __restrict__ noise,
                                                        const float* __restrict__ g,
                                                        const float* __restrict__ colsum,
                                                        const int* __restrict__ t_ptr,
                                                        float* __restrict__ mu,
                                                        int Msk, float hcount) {
    int row = blockIdx.x;
    int tid = threadIdx.x;
    const f32x4* ps = reinterpret_cast<const f32x4*>(sk + (size_t)row * Msk);
    const f32x4* pn = reinterpret_cast<const f32x4*>(noise + (size_t)row * Msk);
    int n4 = Msk >> 2;

    float ss = 0.0f, sn = 0.0f;
    int base = 0;
    for (; base + 2048 <= n4; base += 2048) {
        const f32x4* qs = ps + base + tid;
        const f32x4* qn = pn + base + tid;
        f32x4 a0 = __builtin_nontemporal_load(qs + 0 * 256);
        f32x4 a1 = __builtin_nontemporal_load(qs + 1 * 256);
        f32x4 a2 = __builtin_nontemporal_load(qs + 2 * 256);
        f32x4 a3 = __builtin_nontemporal_load(qs + 3 * 256);
        f32x4 a4 = __builtin_nontemporal_load(qs + 4 * 256);
        f32x4 a5 = __builtin_nontemporal_load(qs + 5 * 256);
        f32x4 a6 = __builtin_nontemporal_load(qs + 6 * 256);
        f32x4 a7 = __builtin_nontemporal_load(qs + 7 * 256);
        f32x4 b0 = __builtin_nontemporal_load(qn + 0 * 256);
        f32x4 b1 = __builtin_nontemporal_load(qn + 1 * 256);
        f32x4 b2 = __builtin_nontemporal_load(qn + 2 * 256);
        f32x4 b3 = __builtin_nontemporal_load(qn + 3 * 256);
        f32x4 b4 = __builtin_nontemporal_load(qn + 4 * 256);
        f32x4 b5 = __builtin_nontemporal_load(qn + 5 * 256);
        f32x4 b6 = __builtin_nontemporal_load(qn + 6 * 256);
        f32x4 b7 = __builtin_nontemporal_load(qn + 7 * 256);
        __builtin_amdgcn_sched_barrier(0);
        float s0 = (a0.x + a0.y) + (a0.z + a0.w);
        float s1 = (a1.x + a1.y) + (a1.z + a1.w);
        float s2 = (a2.x + a2.y) + (a2.z + a2.w);
        float s3 = (a3.x + a3.y) + (a3.z + a3.w);
        float s4 = (a4.x + a4.y) + (a4.z + a4.w);
        float s5 = (a5.x + a5.y) + (a5.z + a5.w);
        float s6 = (a6.x + a6.y) + (a6.z + a6.w);
        float s7 = (a7.x + a7.y) + (a7.z + a7.w);
        float t0 = (b0.x + b0.y) + (b0.z + b0.w);
        float t1 = (b1.x + b1.y) + (b1.z + b1.w);
        float t2 = (b2.x + b2.y) + (b2.z + b2.w);
        float t3 = (b3.x + b3.y) + (b3.z + b3.w);
        float t4 = (b4.x + b4.y) + (b4.z + b4.w);
        float t5 = (b5.x + b5.y) + (b5.z + b5.w);
        float t6 = (b6.x + b6.y) + (b6.z + b6.w);
        float t7 = (b7.x + b7.y) + (b7.z + b7.w);
        ss += ((s0 + s1) + (s2 + s3)) + ((s4 + s5) + (s6 + s7));
        sn += ((t0 + t1) + (t2 + t3)) + ((t4 + t5) + (t6 + t7));
    }
    for (int i = base + tid; i < n4; i += 256) {
        f32x4 v = ps[i];
        f32x4 w = pn[i];
        ss += (v.x + v.y) + (v.z + v.w);
        sn += (w.x + w.y) + (w.z + w.w);
    }

#pragma unroll
    for (int off = 32; off > 0; off >>= 1) {
        ss += __shfl_down(ss, off);
        sn += __shfl_down(sn, off);
    }
    __shared__ float red[2][4];
    int wid = tid >> 6;
    if ((tid & 63) == 0) { red[0][wid] = ss; red[1][wid] = sn; }
    __syncthreads();
    if (tid == 0) {
        float sst = (red[0][0] + red[0][1]) + (red[0][2] + red[0][3]);
        float snt = (red[1][0] + red[1][1]) + (red[1][2] + red[1][3]);
        float t = (float)(*t_ptr);
        float decay = __expf(-t / 64.0f);
        float kappa = 1.0f / t;
        float gc = g[row];
        float acc = decay * sst + 0.01f * snt;
        mu[row] = gc / (float)Msk * (acc + kappa * gc * colsum[row] * hcount);
    }
}

// out[i,k] = b[k] (atomic-fallback path only)
__global__ __launch_bounds__(256) void init_out_kernel(const float* __restrict__ bias,
                                                       float* __restrict__ out,
                                                       int Kdim, int total) {
    int i = blockIdx.x * 256 + threadIdx.x;
    if (i < total) out[i] = bias[i % Kdim];
}

// Split-bf16 MFMA GEMM: s*(x-mu) @ W over the z-th C-chunk.
// grid (B/64, ceil(K/64), SPLITK), 256 threads = 4 waves, each wave a 32x32
// quadrant via 2x2 mfma_f32_16x16x32_bf16 frags x 3 passes (hh, hl, lh).
template <bool ATOMIC>
__global__ __launch_bounds__(256, 4) void gemm_kernel(const float* __restrict__ x,
                                                      const float* __restrict__ W,
                                                      const float* __restrict__ mu,
                                                      float* __restrict__ outp,
                                                      int Bdim, int Cdim, int Kdim,
                                                      int Kc, float s) {
    // [hi/lo][row][k], 40-elem rows: 80 B stride (b128-aligned, 20-bank step)
    __shared__ short As[2][64][40];
    __shared__ short Bs[2][64][40];

    const int tid = threadIdx.x;
    const int lane = tid & 63;
    const int w = tid >> 6;
    const int wr = w >> 1;          // wave row quadrant (0-1)
    const int wc = w & 1;           // wave col quadrant (0-1)
    const int row0 = blockIdx.x * 64;
    const int col0 = blockIdx.y * 64;
    const int cbeg = blockIdx.z * Kc;

    // A staging: thread -> (m, 8 consecutive k)
    const int am = tid >> 2;            // 0..63
    const int ac8 = (tid & 3) * 8;      // 0,8,16,24
    // B staging: thread -> (n, 8 consecutive k), 8 coalesced scalar W loads
    const int bn = tid & 63;            // 0..63
    const int bk8 = (tid >> 6) * 8;     // 0,8,16,24
    const int bcol = col0 + bn;
    const bool bok = bcol < Kdim;

    // frag read coords
    const int fr = lane & 15;
    const int fk8 = (lane >> 4) * 8;

    f32x4 acc[2][2] = {};

    for (int it = 0; it < Kc; it += 32) {
        const int c0 = cbeg + it;
        // ---- global loads ----
        const float* xr = &x[(size_t)(row0 + am) * Cdim + c0 + ac8];
        f32x4 xa = *reinterpret_cast<const f32x4*>(xr);
        f32x4 xb = *reinterpret_cast<const f32x4*>(xr + 4);
        f32x4 ma = *reinterpret_cast<const f32x4*>(&mu[c0 + ac8]);
        f32x4 mb = *reinterpret_cast<const f32x4*>(&mu[c0 + ac8 + 4]);
        float wv[8];
#pragma unroll
        for (int j = 0; j < 8; ++j)
            wv[j] = bok ? W[(size_t)(c0 + bk8 + j) * Kdim + bcol] : 0.0f;

        __syncthreads();   // previous iteration's frag reads done

        // ---- convert + stage A ----
        float av[8];
        av[0] = s * (xa.x - ma.x); av[1] = s * (xa.y - ma.y);
        av[2] = s * (xa.z - ma.z); av[3] = s * (xa.w - ma.w);
        av[4] = s * (xb.x - mb.x); av[5] = s * (xb.y - mb.y);
        av[6] = s * (xb.z - mb.z); av[7] = s * (xb.w - mb.w);
        bf16x8 ah, al;
#pragma unroll
        for (int j = 0; j < 8; ++j) {
            short h = f2bf(av[j]);
            ah[j] = h;
            al[j] = f2bf(av[j] - bf2f(h));
        }
        *reinterpret_cast<bf16x8*>(&As[0][am][ac8]) = ah;
        *reinterpret_cast<bf16x8*>(&As[1][am][ac8]) = al;

        // ---- convert + stage B (transposed to [n][k]) ----
        bf16x8 bh, bl;
#pragma unroll
        for (int j = 0; j < 8; ++j) {
            short h = f2bf(wv[j]);
            bh[j] = h;
            bl[j] = f2bf(wv[j] - bf2f(h));
        }
        *reinterpret_cast<bf16x8*>(&Bs[0][bn][bk8]) = bh;
        *reinterpret_cast<bf16x8*>(&Bs[1][bn][bk8]) = bl;

        __syncthreads();

        // ---- fragment reads (8x ds_read_b128) ----
        bf16x8 afr[2][2], bfr[2][2];
#pragma unroll
        for (int h = 0; h < 2; ++h) {
#pragma unroll
            for (int f = 0; f < 2; ++f) {
                afr[h][f] = *reinterpret_cast<const bf16x8*>(
                    &As[h][wr * 32 + f * 16 + fr][fk8]);
                bfr[h][f] = *reinterpret_cast<const bf16x8*>(
                    &Bs[h][wc * 32 + f * 16 + fr][fk8]);
            }
        }

        // ---- 12 MFMA: hh + hl + lh ----
#pragma unroll
        for (int mf = 0; mf < 2; ++mf) {
#pragma unroll
            for (int nf = 0; nf < 2; ++nf) {
                acc[mf][nf] = __builtin_amdgcn_mfma_f32_16x16x32_bf16(
                    afr[0][mf], bfr[0][nf], acc[mf][nf], 0, 0, 0);
                acc[mf][nf] = __builtin_amdgcn_mfma_f32_16x16x32_bf16(
                    afr[0][mf], bfr[1][nf], acc[mf][nf], 0, 0, 0);
                acc[mf][nf] = __builtin_amdgcn_mfma_f32_16x16x32_bf16(
                    afr[1][mf], bfr[0][nf], acc[mf][nf], 0, 0, 0);
            }
        }
    }

    // ---- epilogue: C/D layout col=lane&15, row=(lane>>4)*4+reg ----
#pragma unroll
    for (int mf = 0; mf < 2; ++mf) {
#pragma unroll
        for (int nf = 0; nf < 2; ++nf) {
#pragma unroll
            for (int r = 0; r < 4; ++r) {
                int row = row0 + wr * 32 + mf * 16 + (lane >> 4) * 4 + r;
                int col = col0 + wc * 32 + nf * 16 + (lane & 15);
                if (col < Kdim) {
                    if (ATOMIC)
                        atomicAdd(&outp[(size_t)row * Kdim + col], acc[mf][nf][r]);
                    else
                        outp[((size_t)blockIdx.z * Bdim + row) * Kdim + col] =
                            acc[mf][nf][r];
                }
            }
        }
    }
}

// out = bias + sum_z partial[z]; flat float4 over B*K
__global__ __launch_bounds__(256) void reduce_kernel(const float* __restrict__ part,
                                                     const float* __restrict__ bias,
                                                     float* __restrict__ out,
                                                     int total4, int Kdim, int perz) {
    int i = blockIdx.x * 256 + threadIdx.x;
    if (i >= total4) return;
    const float4* p4 = reinterpret_cast<const float4*>(part);
    float4 sum = p4[i];
#pragma unroll
    for (int z = 1; z < SPLITK; ++z) {
        float4 v = p4[(size_t)z * (perz >> 2) + i];
        sum.x += v.x; sum.y += v.y; sum.z += v.z; sum.w += v.w;
    }
    int e = i * 4;
    sum.x += bias[(e + 0) % Kdim];
    sum.y += bias[(e + 1) % Kdim];
    sum.z += bias[(e + 2) % Kdim];
    sum.w += bias[(e + 3) % Kdim];
    reinterpret_cast<float4*>(out)[i] = sum;
}

extern "C" void kernel_launch(void* const* d_in, const int* in_sizes, int n_in,
                              void* d_out, int out_size, void* d_ws, size_t ws_size,
                              hipStream_t stream) {
    const float* x      = (const float*)d_in[0];   // [B, C]
    const float* sk     = (const float*)d_in[1];   // [C, M]
    const float* g      = (const float*)d_in[2];   // [C]
    const float* noise  = (const float*)d_in[3];   // [C, M]
    const float* W      = (const float*)d_in[4];   // [C, K]
    const float* bias   = (const float*)d_in[5];   // [K]
    // d_in[6] = h: only its LENGTH matters (sum of bincount == len(h))
    const int* t_ptr    = (const int*)d_in[7];

    int C    = in_sizes[2];
    int Bdim = in_sizes[0] / C;
    int Msk  = in_sizes[1] / C;
    int Kdim = in_sizes[5];
    float hcount = (float)in_sizes[6];

    float* colsum = (float*)d_ws;            // C floats
    float* mu     = colsum + C;              // C floats
    float* part   = mu + C;                  // SPLITK*B*K floats (if it fits)

    size_t need = (size_t)(2 * C + SPLITK * Bdim * Kdim) * sizeof(float);
    bool use_partial = ws_size >= need;

    float s = (float)(1.0 / ((1.0 + 1e-6) * sqrt(0.375 + 1e-6)));
    int Kc = C / SPLITK;

    // 1) colsum = 0
    hipMemsetAsync(colsum, 0, C * sizeof(float), stream);
    // 2) colsum of x (1024 blocks, 8 batched loads/thread)
    {
        dim3 grid(C / 256, Bdim / 8);
        colsum_kernel<<<grid, 256, 0, stream>>>(x, colsum, C);
    }
    // 3) weighted rowsums + fused mu finalize (16 loads in flight/thread)
    rowsum_kernel<<<C, 256, 0, stream>>>(sk, noise, g, colsum, t_ptr, mu, Msk, hcount);
    // 4+5) MFMA GEMM (split-K) and combine
    dim3 ggrid(Bdim / 64, (Kdim + 63) / 64, SPLITK);
    if (use_partial) {
        gemm_kernel<false><<<ggrid, 256, 0, stream>>>(x, W, mu, part, Bdim, C, Kdim,
                                                      Kc, s);
        int perz = Bdim * Kdim;
        int total4 = perz / 4;
        reduce_kernel<<<(total4 + 255) / 256, 256, 0, stream>>>(part, bias,
                                                                (float*)d_out,
                                                                total4, Kdim, perz);
    } else {
        int total = Bdim * Kdim;
        init_out_kernel<<<(total + 255) / 256, 256, 0, stream>>>(bias, (float*)d_out,
                                                                 Kdim, total);
        gemm_kernel<true><<<ggrid, 256, 0, stream>>>(x, W, mu, (float*)d_out, Bdim, C,
                                                     Kdim, Kc, s);
    }
}